// Round 4
// baseline (26.183 us; speedup 1.0000x reference)
//
#include <hip/hip_runtime.h>

#define NS 128   // samples per ray
#define NF 32    // features
#define RPW 2    // rays per wave (software-pipelined)

// One wave per RPW consecutive rays. Block = 256 threads = 4 waves.
// Cross-ray pipeline: while consuming feats of ray r, the depth/sigma loads of
// ray r+1 are already in flight; the serial scan of r+1 then runs with zero
// memory wait, overlapping the feats stream of r (in-order vmcnt retirement).
__global__ __launch_bounds__(256)
void volren_kernel(const float* __restrict__ depths,   // [n_rays, NS]
                   const float* __restrict__ sigma,    // [n_rays, NS]
                   const float* __restrict__ feats,    // [n_rays, NS, NF]
                   const int*   __restrict__ valid,    // [n_rays]
                   float* __restrict__ out_feats,      // [n_rays, NF]
                   float* __restrict__ out_depth,      // [n_rays]
                   float* __restrict__ out_ws,         // [n_rays]
                   float* __restrict__ out_alpha,      // [n_rays]
                   int n_rays)
{
    const int wave = threadIdx.x >> 6;
    const int lane = threadIdx.x & 63;
    const int gid  = blockIdx.x * 4 + wave;
    const int ray0 = gid * RPW;
    if (ray0 >= n_rays) return;

    const int j = lane >> 3;       // sample-sub index in [0,8)
    const int q = lane & 7;        // float4 quad index in [0,8)

    // ---------- prefetch depths/sigma for ray0 ----------
    float d_lo, d_hi, s_lo, s_hi;
    {
        const float* dp = depths + (size_t)ray0 * NS;
        const float* sp = sigma  + (size_t)ray0 * NS;
        d_lo = dp[lane]; d_hi = dp[lane + 64];
        s_lo = sp[lane]; s_hi = sp[lane + 64];
    }

    #pragma unroll
    for (int r = 0; r < RPW; ++r) {
        const int ray = ray0 + r;

        // ---------- issue the feats stream (93% of bytes): 16 x float4 / lane ----------
        const float4* fptr = (const float4*)(feats + (size_t)ray * NS * NF);
        float4 v0[8], v1[8];
        #pragma unroll
        for (int it = 0; it < 8; ++it)
            v0[it] = fptr[(it * 8 + j) * 8 + q];
        #pragma unroll
        for (int it = 0; it < 8; ++it)
            v1[it] = fptr[((it + 8) * 8 + j) * 8 + q];

        // ---------- issue next ray's depths/sigma (hidden under feats consumption) ----------
        float nd_lo = 0.f, nd_hi = 0.f, ns_lo = 0.f, ns_hi = 0.f;
        if (r + 1 < RPW) {
            const float* dp = depths + (size_t)(ray + 1) * NS;
            const float* sp = sigma  + (size_t)(ray + 1) * NS;
            nd_lo = dp[lane]; nd_hi = dp[lane + 64];
            ns_lo = sp[lane]; ns_hi = sp[lane + 64];
        }

        // ---------- phase 1: free energy + wave-wide inclusive scan ----------
        float d_lo_nb = __shfl(d_lo, (lane + 1) & 63, 64);
        float d_hi_nb = __shfl(d_hi, (lane + 1) & 63, 64);
        float d64     = __shfl(d_hi, 0, 64);
        float d_lo_n  = (lane == 63) ? d64  : d_lo_nb;
        float d_hi_n  = (lane == 63) ? d_hi : d_hi_nb;   // last dist = 0

        float fe_lo = (d_lo_n - d_lo) * s_lo;
        float fe_hi = (d_hi_n - d_hi) * s_hi;

        float c_lo = fe_lo;
        #pragma unroll
        for (int off = 1; off < 64; off <<= 1) {
            float t = __shfl_up(c_lo, off, 64);
            if (lane >= off) c_lo += t;
        }
        float tot_lo = __shfl(c_lo, 63, 64);
        float c_hi = fe_hi;
        #pragma unroll
        for (int off = 1; off < 64; off <<= 1) {
            float t = __shfl_up(c_hi, off, 64);
            if (lane >= off) c_hi += t;
        }
        c_hi += tot_lo;

        // w = alpha * exp(fe - cum) = exp(fe - cum) - exp(-cum)
        float w_lo = expf(fe_lo - c_lo) - expf(-c_lo);
        float w_hi = expf(fe_hi - c_hi) - expf(-c_hi);
        float a_lo = 1.0f - expf(-fe_lo);
        float a_hi = 1.0f - expf(-fe_hi);

        // scalar reductions: depth, alpha, weight-sum (overlap feats flight)
        float dsum = w_lo * d_lo + w_hi * d_hi;
        float asum = w_lo * a_lo + w_hi * a_hi;
        float wsum = w_lo + w_hi;
        #pragma unroll
        for (int m = 1; m < 64; m <<= 1) {
            dsum += __shfl_xor(dsum, m, 64);
            asum += __shfl_xor(asum, m, 64);
            wsum += __shfl_xor(wsum, m, 64);
        }

        const float maskf = valid[ray] ? 1.0f : 0.0f;
        if (lane == 0) {
            out_depth[ray] = dsum * maskf;
            out_ws[ray]    = wsum * maskf;
            out_alpha[ray] = asum * maskf;
        }

        // ---------- phase 2: feats contraction (weights via in-wave shuffle) ----------
        float4 acc = make_float4(0.f, 0.f, 0.f, 0.f);
        #pragma unroll
        for (int it = 0; it < 8; ++it) {
            const float w = __shfl(w_lo, it * 8 + j, 64);
            acc.x += w * v0[it].x;
            acc.y += w * v0[it].y;
            acc.z += w * v0[it].z;
            acc.w += w * v0[it].w;
        }
        #pragma unroll
        for (int it = 0; it < 8; ++it) {
            const float w = __shfl(w_hi, it * 8 + j, 64);
            acc.x += w * v1[it].x;
            acc.y += w * v1[it].y;
            acc.z += w * v1[it].z;
            acc.w += w * v1[it].w;
        }
        // reduce across the 8 sample-sub lanes (stride 8)
        #pragma unroll
        for (int m = 8; m < 64; m <<= 1) {
            acc.x += __shfl_xor(acc.x, m, 64);
            acc.y += __shfl_xor(acc.y, m, 64);
            acc.z += __shfl_xor(acc.z, m, 64);
            acc.w += __shfl_xor(acc.w, m, 64);
        }
        if (j == 0) {
            float4 o = make_float4(acc.x * maskf, acc.y * maskf,
                                   acc.z * maskf, acc.w * maskf);
            ((float4*)(out_feats + (size_t)ray * NF))[q] = o;
        }

        // rotate pipeline registers
        if (r + 1 < RPW) {
            d_lo = nd_lo; d_hi = nd_hi; s_lo = ns_lo; s_hi = ns_hi;
        }
    }
}

extern "C" void kernel_launch(void* const* d_in, const int* in_sizes, int n_in,
                              void* d_out, int out_size, void* d_ws, size_t ws_size,
                              hipStream_t stream) {
    const float* depths = (const float*)d_in[0];   // sampled_depths [B,R,S]
    const float* sigma  = (const float*)d_in[1];   // sigma          [B,R,S]
    const float* feats  = (const float*)d_in[2];   // feats          [B,R,S,F]
    // d_in[3] = max_depths (unused by the reference math)
    const int*   valid  = (const int*)d_in[4];     // valid_rays     [B,R]

    const int n_rays = in_sizes[4];                // B*R = 8192

    float* out       = (float*)d_out;
    float* out_feats = out;                               // [n_rays, NF]
    float* out_depth = out + (size_t)n_rays * NF;         // [n_rays]
    float* out_ws    = out_depth + n_rays;                // [n_rays]
    float* out_alpha = out_ws + n_rays;                   // [n_rays]

    const int rays_per_block = 4 * RPW;
    const int grid = (n_rays + rays_per_block - 1) / rays_per_block;
    volren_kernel<<<grid, 256, 0, stream>>>(depths, sigma, feats, valid,
                                            out_feats, out_depth, out_ws,
                                            out_alpha, n_rays);
}

// Round 5
// 18.307 us; speedup vs baseline: 1.4302x; 1.4302x over previous
//
#include <hip/hip_runtime.h>

#define NS 128   // samples per ray
#define NF 32    // features
#define RPW 2    // rays per wave

// One wave per RPW consecutive rays. Block = 256 threads = 4 waves.
// Key insight: outputs of invalid rays are exactly zero -> skip ALL input
// traffic for them (valid_rays ~50% false in this workload). valid[ray] is
// wave-uniform -> scalar branch, no divergence.
__global__ __launch_bounds__(256)
void volren_kernel(const float* __restrict__ depths,   // [n_rays, NS]
                   const float* __restrict__ sigma,    // [n_rays, NS]
                   const float* __restrict__ feats,    // [n_rays, NS, NF]
                   const int*   __restrict__ valid,    // [n_rays]
                   float* __restrict__ out_feats,      // [n_rays, NF]
                   float* __restrict__ out_depth,      // [n_rays]
                   float* __restrict__ out_ws,         // [n_rays]
                   float* __restrict__ out_alpha,      // [n_rays]
                   int n_rays)
{
    const int wave = threadIdx.x >> 6;
    const int lane = threadIdx.x & 63;
    const int gid  = blockIdx.x * 4 + wave;
    const int ray0 = gid * RPW;
    if (ray0 >= n_rays) return;

    const int j = lane >> 3;       // sample-sub index in [0,8)
    const int q = lane & 7;        // float4 quad index in [0,8)

    #pragma unroll
    for (int r = 0; r < RPW; ++r) {
        const int ray = ray0 + r;

        if (valid[ray] == 0) {
            // outputs are exactly zero; no input bytes needed
            if (j == 0)
                ((float4*)(out_feats + (size_t)ray * NF))[q] =
                    make_float4(0.f, 0.f, 0.f, 0.f);
            if (lane == 0) {
                out_depth[ray] = 0.f;
                out_ws[ray]    = 0.f;
                out_alpha[ray] = 0.f;
            }
            continue;
        }

        // ---------- issue scan inputs first (vmcnt retires in order) ----------
        const float* dp = depths + (size_t)ray * NS;
        const float* sp = sigma  + (size_t)ray * NS;
        float d_lo = dp[lane];
        float d_hi = dp[lane + 64];
        float s_lo = sp[lane];
        float s_hi = sp[lane + 64];

        // ---------- issue the feats stream: 16 x float4 / lane ----------
        const float4* fptr = (const float4*)(feats + (size_t)ray * NS * NF);
        float4 v0[8], v1[8];
        #pragma unroll
        for (int it = 0; it < 8; ++it)
            v0[it] = fptr[(it * 8 + j) * 8 + q];
        #pragma unroll
        for (int it = 0; it < 8; ++it)
            v1[it] = fptr[((it + 8) * 8 + j) * 8 + q];

        // ---------- phase 1: free energy + wave-wide inclusive scan ----------
        float d_lo_nb = __shfl(d_lo, (lane + 1) & 63, 64);
        float d_hi_nb = __shfl(d_hi, (lane + 1) & 63, 64);
        float d64     = __shfl(d_hi, 0, 64);
        float d_lo_n  = (lane == 63) ? d64  : d_lo_nb;
        float d_hi_n  = (lane == 63) ? d_hi : d_hi_nb;   // last dist = 0

        float fe_lo = (d_lo_n - d_lo) * s_lo;
        float fe_hi = (d_hi_n - d_hi) * s_hi;

        float c_lo = fe_lo;
        #pragma unroll
        for (int off = 1; off < 64; off <<= 1) {
            float t = __shfl_up(c_lo, off, 64);
            if (lane >= off) c_lo += t;
        }
        float tot_lo = __shfl(c_lo, 63, 64);
        float c_hi = fe_hi;
        #pragma unroll
        for (int off = 1; off < 64; off <<= 1) {
            float t = __shfl_up(c_hi, off, 64);
            if (lane >= off) c_hi += t;
        }
        c_hi += tot_lo;

        // w = alpha * exp(fe - cum) = exp(fe - cum) - exp(-cum)
        float w_lo = expf(fe_lo - c_lo) - expf(-c_lo);
        float w_hi = expf(fe_hi - c_hi) - expf(-c_hi);
        float a_lo = 1.0f - expf(-fe_lo);
        float a_hi = 1.0f - expf(-fe_hi);

        // scalar reductions: depth, alpha, weight-sum (overlap feats flight)
        float dsum = w_lo * d_lo + w_hi * d_hi;
        float asum = w_lo * a_lo + w_hi * a_hi;
        float wsum = w_lo + w_hi;
        #pragma unroll
        for (int m = 1; m < 64; m <<= 1) {
            dsum += __shfl_xor(dsum, m, 64);
            asum += __shfl_xor(asum, m, 64);
            wsum += __shfl_xor(wsum, m, 64);
        }
        if (lane == 0) {
            out_depth[ray] = dsum;
            out_ws[ray]    = wsum;
            out_alpha[ray] = asum;
        }

        // ---------- phase 2: feats contraction (weights via in-wave shuffle) ----------
        float4 acc = make_float4(0.f, 0.f, 0.f, 0.f);
        #pragma unroll
        for (int it = 0; it < 8; ++it) {
            const float w = __shfl(w_lo, it * 8 + j, 64);
            acc.x += w * v0[it].x;
            acc.y += w * v0[it].y;
            acc.z += w * v0[it].z;
            acc.w += w * v0[it].w;
        }
        #pragma unroll
        for (int it = 0; it < 8; ++it) {
            const float w = __shfl(w_hi, it * 8 + j, 64);
            acc.x += w * v1[it].x;
            acc.y += w * v1[it].y;
            acc.z += w * v1[it].z;
            acc.w += w * v1[it].w;
        }
        // reduce across the 8 sample-sub lanes (stride 8)
        #pragma unroll
        for (int m = 8; m < 64; m <<= 1) {
            acc.x += __shfl_xor(acc.x, m, 64);
            acc.y += __shfl_xor(acc.y, m, 64);
            acc.z += __shfl_xor(acc.z, m, 64);
            acc.w += __shfl_xor(acc.w, m, 64);
        }
        if (j == 0)
            ((float4*)(out_feats + (size_t)ray * NF))[q] = acc;
    }
}

extern "C" void kernel_launch(void* const* d_in, const int* in_sizes, int n_in,
                              void* d_out, int out_size, void* d_ws, size_t ws_size,
                              hipStream_t stream) {
    const float* depths = (const float*)d_in[0];   // sampled_depths [B,R,S]
    const float* sigma  = (const float*)d_in[1];   // sigma          [B,R,S]
    const float* feats  = (const float*)d_in[2];   // feats          [B,R,S,F]
    // d_in[3] = max_depths (unused by the reference math)
    const int*   valid  = (const int*)d_in[4];     // valid_rays     [B,R]

    const int n_rays = in_sizes[4];                // B*R = 8192

    float* out       = (float*)d_out;
    float* out_feats = out;                               // [n_rays, NF]
    float* out_depth = out + (size_t)n_rays * NF;         // [n_rays]
    float* out_ws    = out_depth + n_rays;                // [n_rays]
    float* out_alpha = out_ws + n_rays;                   // [n_rays]

    const int rays_per_block = 4 * RPW;
    const int grid = (n_rays + rays_per_block - 1) / rays_per_block;
    volren_kernel<<<grid, 256, 0, stream>>>(depths, sigma, feats, valid,
                                            out_feats, out_depth, out_ws,
                                            out_alpha, n_rays);
}